// Round 12
// baseline (165.506 us; speedup 1.0000x reference)
//
#include <hip/hip_runtime.h>
#include <hip/hip_bf16.h>
#include <stdint.h>

#define Bsz 2
#define NT  2048
#define DM  768
#define NH  12
#define HD  64
#define MT  (Bsz * NT)   // 4096 tokens total
#define NCAT (3 * DM)    // 2304 concatenated Q,K,V output cols

typedef float    f32x4  __attribute__((ext_vector_type(4)));
typedef float    f32x16 __attribute__((ext_vector_type(16)));
typedef short    s16x8  __attribute__((ext_vector_type(8)));
typedef _Float16 f16x8  __attribute__((ext_vector_type(8)));
typedef int      v2i    __attribute__((ext_vector_type(2)));

#define GLOBAL_AS __attribute__((address_space(1)))
#define SHARED_AS __attribute__((address_space(3)))
#define LOG2E 1.44269504088896f

__device__ inline unsigned short f2h(float f) {
    union { _Float16 h; unsigned short u; } c; c.h = (_Float16)f; return c.u;
}
__device__ inline f16x8 ldh(const short* p) {
    return __builtin_bit_cast(f16x8, *(const s16x8*)p);
}
__device__ inline float exp2i(float x) {   // raw v_exp_f32: 2^x, 1 instruction
    float r;
    asm("v_exp_f32 %0, %1" : "=v"(r) : "v"(x));
    return r;
}
__device__ inline int cvtpkh(float lo, float hi_) {   // packs (lo,hi) -> 2xf16 dword
    int r;
    asm("v_cvt_pkrtz_f16_f32 %0, %1, %2" : "=v"(r) : "v"(lo), "v"(hi_));
    return r;
}
__device__ inline void plswap(int& a, int& b) {
    v2i r = __builtin_amdgcn_permlane32_swap(a, b, false, false);
    a = r[0]; b = r[1];
}
__device__ inline f16x8 mk8(int a, int b, int c, int d) {
    union { int i[4]; f16x8 v; } u;
    u.i[0] = a; u.i[1] = b; u.i[2] = c; u.i[3] = d;
    return u.v;
}
#define mfma32 __builtin_amdgcn_mfma_f32_32x32x16_f16
#define mfma16 __builtin_amdgcn_mfma_f32_16x16x32_f16

// ---------------- conversion kernels (f32 -> f16) ----------------

__global__ __launch_bounds__(256) void cvt_x_kernel(const float* __restrict__ x,
                                                    short* __restrict__ xf, int n8) {
    int i = blockIdx.x * blockDim.x + threadIdx.x;
    if (i >= n8) return;
    const float4* p = (const float4*)x + (size_t)i * 2;
    float4 a = p[0], b = p[1];
    float v[8] = {a.x, a.y, a.z, a.w, b.x, b.y, b.z, b.w};
    union { unsigned short s[8]; uint4 q; } H;
#pragma unroll
    for (int j = 0; j < 8; ++j) H.s[j] = f2h(v[j]);
    ((uint4*)xf)[i] = H.q;
}

__global__ __launch_bounds__(256) void cvt_w_kernel(const float* __restrict__ Wq,
                                                    const float* __restrict__ Wk,
                                                    const float* __restrict__ Wv,
                                                    short* __restrict__ Wf, int per8) {
    int i = blockIdx.x * blockDim.x + threadIdx.x;
    if (i >= 3 * per8) return;
    const float* src; int j;
    if (i < per8)          { src = Wq; j = i; }
    else if (i < 2 * per8) { src = Wk; j = i - per8; }
    else                   { src = Wv; j = i - 2 * per8; }
    const float4* p = (const float4*)src + (size_t)j * 2;
    float4 a = p[0], b = p[1];
    float v[8] = {a.x, a.y, a.z, a.w, b.x, b.y, b.z, b.w};
    union { unsigned short s[8]; uint4 q; } H;
#pragma unroll
    for (int t = 0; t < 8; ++t) H.s[t] = f2h(v[t]);
    ((uint4*)Wf)[i] = H.q;
}

// ---------------- QKV projection: y = x @ Wcat^T, all f16 ----------------
// Q is pre-scaled by log2(e) so attention softmax runs in base-2 domain
// (exp == single v_exp_f32). 128x128 tile; 4 waves; BK=32; LDS 32 KB dbuf;
// global_load_lds width=16, linear LDS dest.

#define BM 128
#define BK 32
#define KSTEPS (DM / BK)   // 24

__global__ __launch_bounds__(256, 2) void qkv_proj_kernel(
        const short* __restrict__ xf, const short* __restrict__ Wf,
        short* __restrict__ Qf, short* __restrict__ Kf, short* __restrict__ Vf) {
    __shared__ short lds[2][2][BM * BK];   // [dbuf][A,B][row*32+k]

    const int tid = threadIdx.x;
    const int w = tid >> 6, lane = tid & 63;
    const int l15 = lane & 15, lg = lane >> 4;
    const int wr = w >> 1, wc = w & 1;

    const int tile_m = blockIdx.x * BM;
    const int tile_n = blockIdx.y * BM;    // concatenated col base

    const int arr = w >> 1, hlf = w & 1;
    const int srow = lane >> 2;            // 0..15
    const int scol = (lane & 3) * 8;       // element offset in row
    const short* gsrc = (arr == 0) ? xf + (size_t)tile_m * DM
                                   : Wf + (size_t)tile_n * DM;
    const short* gsrc_lane = gsrc + (size_t)(hlf * 64 + srow) * DM + scol;

    f32x4 zero4 = {0.f, 0.f, 0.f, 0.f};
    f32x4 acc[4][4];
#pragma unroll
    for (int i = 0; i < 4; ++i)
#pragma unroll
        for (int j = 0; j < 4; ++j) acc[i][j] = zero4;

    auto stage = [&](int buf, int kt) {
        const short* g = gsrc_lane + kt * BK;
#pragma unroll
        for (int j = 0; j < 4; ++j) {
            __builtin_amdgcn_global_load_lds(
                (const GLOBAL_AS void*)(g + (size_t)j * 16 * DM),
                (SHARED_AS void*)(&lds[buf][arr][(hlf * 64 + j * 16) * BK]),
                16, 0, 0);
        }
    };

    stage(0, 0);
    int cur = 0;
    for (int kt = 0; kt < KSTEPS; ++kt) {
        __syncthreads();                       // buf[cur] staged; prior reads drained
        if (kt + 1 < KSTEPS) stage(cur ^ 1, kt + 1);   // flies under the MFMAs

        f16x8 a[4], b[4];
#pragma unroll
        for (int f = 0; f < 4; ++f) {
            a[f] = ldh(&lds[cur][0][(wr * 64 + f * 16 + l15) * BK + lg * 8]);
            b[f] = ldh(&lds[cur][1][(wc * 64 + f * 16 + l15) * BK + lg * 8]);
        }
#pragma unroll
        for (int mf = 0; mf < 4; ++mf)
#pragma unroll
            for (int nf = 0; nf < 4; ++nf)
                acc[mf][nf] = mfma16(a[mf], b[nf], acc[mf][nf], 0, 0, 0);
        cur ^= 1;
    }

    // ---- epilogue ----
    const int zq = tile_n / DM;            // 0=Q 1=K 2=V (tiles never straddle)
    const int ncol0 = tile_n % DM;
#pragma unroll
    for (int mf = 0; mf < 4; ++mf) {
#pragma unroll
        for (int nf = 0; nf < 4; ++nf) {
            int col = ncol0 + wc * 64 + nf * 16 + l15;
            int h = col >> 6, dh = col & 63;
            int m0 = tile_m + wr * 64 + mf * 16 + lg * 4;
            int b2 = m0 >> 11, nt0 = m0 & (NT - 1);
            int bh_ = b2 * NH + h;
            if (zq == 2) {
                union { short s[4]; short4 v; } pk;
#pragma unroll
                for (int r = 0; r < 4; ++r) pk.s[r] = (short)f2h(acc[mf][nf][r]);
                *(short4*)&Vf[((size_t)bh_ * HD + dh) * NT + nt0] = pk.v;  // V transposed
            } else {
                short* Hp = (zq == 0) ? Qf : Kf;
                float scl = (zq == 0) ? LOG2E : 1.0f;   // Q in log2-domain
#pragma unroll
                for (int r = 0; r < 4; ++r) {
                    size_t oidx = ((size_t)bh_ * NT + nt0 + r) * HD + dh;
                    Hp[oidx] = (short)f2h(acc[mf][nf][r] * scl);
                }
            }
        }
    }
}

// ---------------- attention partials: split-KV flash, f16, log2-domain ----------
// grid (72, B*H): slot s -> (qb, seg); nseg(qb) = qb/2+1, SEGT=4 tiles of 64
// -> every slot has 2-4 tiles (balanced). Per block: 4 waves x 32 q-rows,
// swapped QK^T 32x32, lane-local softmax (1-inst v_exp), wave-uniform mask-skip
// on non-diagonal steps, defer-max THR=8*log2e, dbuf reg-staged K,V^T.
// o0[r] holds O[q-row kr][d-col l31]; per-row scalars go through ds_bpermute(kr).

#define QB  128
#define KVB 64
#define NQB (NT / QB)     // 16
#define SEGT 4            // KV tiles per segment
#define SLOTS 72          // per bh: sum over qb of (qb/2+1)
#define OPA 600           // Op slots aliased into the dead xf/Wf region (exact fit)

__device__ inline short* op_ptr(short* OpA_, short* OpB_, int g) {
    return (g < OPA) ? OpA_ + (size_t)g * (QB * HD)
                     : OpB_ + (size_t)(g - OPA) * (QB * HD);
}

__global__ __launch_bounds__(256) void attn_part_kernel(const short* __restrict__ Qf,
                                                        const short* __restrict__ Kf,
                                                        const short* __restrict__ Vf,
                                                        short* __restrict__ OpA_,
                                                        short* __restrict__ OpB_,
                                                        float2* __restrict__ ml) {
    // slot decode: pairs (2a, 2a+1) each have a+1 segments
    int rem = blockIdx.x, a = 0;
    while (rem >= 2 * (a + 1)) { rem -= 2 * (a + 1); ++a; }
    const int qb  = 2 * a + (rem > a);
    const int seg = (rem > a) ? rem - (a + 1) : rem;
    const int bh = blockIdx.y;
    const int g = bh * SLOTS + blockIdx.x;
    const int tid = threadIdx.x;
    const int w = tid >> 6, lane = tid & 63;
    const int l31 = lane & 31, hi = lane >> 5;

    __shared__ __align__(16) short lds[2][2 * 4096];   // [dbuf][K|V^T][64*64]

    const size_t kvoff = (size_t)bh * NT * HD;
    const short* Kfb = Kf + kvoff;
    const short* Vb  = Vf + (size_t)bh * HD * NT;

    // per-thread staging descriptors: 4 x 16B chunks per tile
    const short* sbase[4]; int sstr[4]; int sdof[4];
#pragma unroll
    for (int k = 0; k < 4; ++k) {
        int c = tid + 256 * k;
        int arr = c >> 9, idx = c & 511;
        int row = idx >> 3, ch = idx & 7;
        if (arr == 0) { sbase[k] = Kfb + (size_t)row * HD + ch * 8; sstr[k] = KVB * HD; }
        else          { sbase[k] = Vb + (size_t)row * NT + ch * 8;  sstr[k] = KVB; }
        sdof[k] = arr * 4096 + row * 64 + ((ch ^ (row & 7)) << 3);
    }

    const int q0w   = qb * QB + w * 32;
    const int qg    = q0w + l31;       // this lane's q-row
    const int qmaxw = q0w + 31;

    // Q fragments (B-operand layout: lane = q-row l31, k = c*16+hi*8); log2-scaled
    f16x8 qf[4];
    const size_t qrow = kvoff + (size_t)qg * HD;
#pragma unroll
    for (int c = 0; c < 4; ++c) qf[c] = ldh(Qf + qrow + c * 16 + hi * 8);

    f32x16 o0{}, o1{};
    float m_run = -1e30f, l_run = 0.f;

    const int t0   = seg * SEGT;
    const int tend = min(t0 + SEGT, 2 * qb + 2);

    {   // prologue: stage tile t0 into buf 0
        uint4 ld0[4];
#pragma unroll
        for (int k = 0; k < 4; ++k) ld0[k] = *(const uint4*)(sbase[k] + (size_t)t0 * sstr[k]);
#pragma unroll
        for (int k = 0; k < 4; ++k) *(uint4*)(&lds[0][sdof[k]]) = ld0[k];
    }

    for (int t = t0; t < tend; ++t) {
        __syncthreads();                      // current buf staged for all waves
        const int cur = (t - t0) & 1;
        const int kv0 = t * KVB;
        const bool haveNext = (t + 1 < tend);
        uint4 ldn[4];
        if (haveNext) {                       // issue early; lands under compute
#pragma unroll
            for (int k = 0; k < 4; ++k)
                ldn[k] = *(const uint4*)(sbase[k] + (size_t)(t + 1) * sstr[k]);
        }

        if (kv0 <= qmaxw) {                   // wave-uniform causal tile skip
            const short* Ks = &lds[cur][0];
            const short* Vs = &lds[cur][4096];
#pragma unroll
            for (int c2 = 0; c2 < 2; ++c2) {
                const int kv0c = kv0 + c2 * 32;
                if (kv0c > qmaxw) continue;   // fully-masked half-step (uniform)
                // ---- S^T = K Q^T (f16, log2-domain) ----
                f32x16 S{};
                const int kvr = c2 * 32 + l31;
                const int swb = kvr * 64, sw7 = kvr & 7;
#pragma unroll
                for (int c = 0; c < 4; ++c) {
                    int off = swb + ((((c << 1) + hi) ^ sw7) << 3);
                    S = mfma32(ldh(&Ks[off]), qf[c], S, 0, 0, 0);
                }
                // ---- mask (diagonal steps only) + lane-local row max ----
                float p[16]; float pmax = -3e38f;
                if (kv0c + 31 > q0w) {        // wave-uniform: step crosses diagonal
#pragma unroll
                    for (int r = 0; r < 16; ++r) {
                        int kvg = kv0c + (r & 3) + 8 * (r >> 2) + 4 * hi;
                        float sv = (kvg > qg) ? -3e38f : S[r];
                        p[r] = sv;
                        pmax = fmaxf(pmax, sv);
                    }
                } else {
#pragma unroll
                    for (int r = 0; r < 16; ++r) { p[r] = S[r]; pmax = fmaxf(pmax, S[r]); }
                }
                pmax = fmaxf(pmax, __shfl_xor(pmax, 32));
                // ---- defer-max online softmax (base-2; THR = 8*log2e) ----
                if (!__all(pmax - m_run <= 11.5416f)) {
                    float mn = fmaxf(m_run, pmax);
                    float al = exp2i(m_run - mn);
                    m_run = mn; l_run *= al;
                    int ai = __builtin_bit_cast(int, al);
#pragma unroll
                    for (int r = 0; r < 16; ++r) {
                        int kr = (r & 3) + 8 * (r >> 2) + 4 * hi;
                        float av = __builtin_bit_cast(float,
                                      __builtin_amdgcn_ds_bpermute(kr << 2, ai));
                        o0[r] *= av; o1[r] *= av;
                    }
                }
                float rs = 0.f;
#pragma unroll
                for (int r = 0; r < 16; ++r) { p[r] = exp2i(p[r] - m_run); rs += p[r]; }
                rs += __shfl_xor(rs, 32);
                l_run += rs;
                // ---- pack P -> PV A-fragments (pkrtz + permlane32_swap) ----
                int cpk[8];
#pragma unroll
                for (int i = 0; i < 8; ++i) cpk[i] = cvtpkh(p[2 * i], p[2 * i + 1]);
                int a0 = cpk[0], b0 = cpk[2]; plswap(a0, b0);
                int a1 = cpk[1], b1 = cpk[3]; plswap(a1, b1);
                int a2 = cpk[4], b2 = cpk[6]; plswap(a2, b2);
                int a3 = cpk[5], b3 = cpk[7]; plswap(a3, b3);
                f16x8 pf[2] = { mk8(a0, a1, b0, b1), mk8(a2, a3, b2, b3) };
                // ---- O += P V ----
#pragma unroll
                for (int kc = 0; kc < 2; ++kc) {
                    int chunk = c2 * 4 + kc * 2 + hi;
                    int off0 = l31 * 64 + ((chunk ^ (l31 & 7)) << 3);
                    int off1 = (32 + l31) * 64 + ((chunk ^ (l31 & 7)) << 3);
                    o0 = mfma32(pf[kc], ldh(&Vs[off0]), o0, 0, 0, 0);
                    o1 = mfma32(pf[kc], ldh(&Vs[off1]), o1, 0, 0, 0);
                }
            }
        }

        if (haveNext) {                       // write next tile into other buffer
#pragma unroll
            for (int k = 0; k < 4; ++k) *(uint4*)(&lds[cur ^ 1][sdof[k]]) = ldn[k];
        }
    }

    // ---- epilogue: normalized partial O (f16) + (m,l) per row ----
    float inv = 1.0f / l_run;
    int ii = __builtin_bit_cast(int, inv);
    short* op = op_ptr(OpA_, OpB_, g);
#pragma unroll
    for (int r = 0; r < 16; ++r) {
        int kr = (r & 3) + 8 * (r >> 2) + 4 * hi;
        float iv = __builtin_bit_cast(float, __builtin_amdgcn_ds_bpermute(kr << 2, ii));
        short* orow = op + (w * 32 + kr) * HD;
        orow[l31]      = (short)f2h(o0[r] * iv);
        orow[32 + l31] = (short)f2h(o1[r] * iv);
    }
    if (hi == 0) {
        float2 v; v.x = m_run; v.y = l_run;   // m in log2-domain
        ml[(size_t)g * QB + w * 32 + l31] = v;
    }
}

// ---------------- combine: merge split-KV partials (base-2 weights) ----------------

__global__ __launch_bounds__(256) void combine_kernel(const short* __restrict__ OpA_,
                                                      const short* __restrict__ OpB_,
                                                      const float2* __restrict__ ml,
                                                      float* __restrict__ out) {
    const int qb = blockIdx.x, bh = blockIdx.y;
    const int b = bh / NH, h = bh % NH;
    const int a = qb >> 1;
    const int nseg = a + 1;
    const int sbase = (a + 1) * (a + (qb & 1));   // cumulative slot base
    const int row = threadIdx.x >> 1;
    const int c0 = (threadIdx.x & 1) * 32;

    float m[8], l[8];
    float M = -3e38f;
    for (int s2 = 0; s2 < nseg; ++s2) {
        float2 t = ml[((size_t)(bh * SLOTS + sbase + s2)) * QB + row];
        m[s2] = t.x; l[s2] = t.y;
        M = fmaxf(M, t.x);
    }
    float wgt[8], L = 0.f;
    for (int s2 = 0; s2 < nseg; ++s2) {
        float e;
        asm("v_exp_f32 %0, %1" : "=v"(e) : "v"(m[s2] - M));   // 2^(m-M), log2-domain
        wgt[s2] = l[s2] * e; L += wgt[s2];
    }
    float invL = 1.0f / L;

    float acc[32];
#pragma unroll
    for (int j = 0; j < 32; ++j) acc[j] = 0.f;
    for (int s2 = 0; s2 < nseg; ++s2) {
        int g = bh * SLOTS + sbase + s2;
        const short* opg = (g < OPA) ? OpA_ + (size_t)g * (QB * HD)
                                     : OpB_ + (size_t)(g - OPA) * (QB * HD);
        const short* oprow = opg + (size_t)row * HD + c0;
        float wg = wgt[s2] * invL;
#pragma unroll
        for (int v = 0; v < 4; ++v) {
            f16x8 d = ldh(oprow + v * 8);
#pragma unroll
            for (int j = 0; j < 8; ++j)
                acc[v * 8 + j] += wg * (float)d[j];
        }
    }
    float* orow = out + ((size_t)(b * NT + qb * QB + row)) * DM + h * HD + c0;
#pragma unroll
    for (int j = 0; j < 32; ++j) orow[j] = acc[j];
}

// ---------------- launch ----------------

extern "C" void kernel_launch(void* const* d_in, const int* in_sizes, int n_in,
                              void* d_out, int out_size, void* d_ws, size_t ws_size,
                              hipStream_t stream) {
    const float* x  = (const float*)d_in[0];
    const float* Wq = (const float*)d_in[1];
    const float* Wk = (const float*)d_in[2];
    const float* Wv = (const float*)d_in[3];
    float* outp = (float*)d_out;

    const size_t MD = (size_t)MT * DM;   // 3,145,728
    const size_t DD = (size_t)DM * DM;   //   589,824

    short* wsp = (short*)d_ws;
    short* xf = wsp;            // MD
    short* Wf = xf + MD;        // 3*DD   (xf+Wf = 4,915,200 shorts = 600 Op slots exactly)
    short* Qf = Wf + 3 * DD;    // MD
    short* Kf = Qf + MD;        // MD
    short* Vf = Kf + MD;        // MD (transposed: [bh][hd][n])
    // Op partials: region A aliases dead xf/Wf (600 slots), region B after Vf.
    short* OpA_ = wsp;
    short* OpB_ = Vf + MD;      // (72*24-600) = 1128 slots x 8192 shorts
    float2* mlp = (float2*)(OpB_ + (size_t)1128 * QB * HD);   // 1728*128 float2

    int n8x = (int)(MD / 8);
    cvt_x_kernel<<<dim3((n8x + 255) / 256), 256, 0, stream>>>(x, xf, n8x);
    int per8 = (int)(DD / 8);
    cvt_w_kernel<<<dim3((3 * per8 + 255) / 256), 256, 0, stream>>>(Wq, Wk, Wv, Wf, per8);
    qkv_proj_kernel<<<dim3(MT / BM, NCAT / BM), 256, 0, stream>>>(xf, Wf, Qf, Kf, Vf);
    attn_part_kernel<<<dim3(SLOTS, Bsz * NH), 256, 0, stream>>>(Qf, Kf, Vf, OpA_, OpB_, mlp);
    combine_kernel<<<dim3(NQB, Bsz * NH), 256, 0, stream>>>(OpA_, OpB_, mlp, outp);
}

// Round 13
// 161.694 us; speedup vs baseline: 1.0236x; 1.0236x over previous
//
#include <hip/hip_runtime.h>
#include <hip/hip_bf16.h>
#include <stdint.h>

#define Bsz 2
#define NT  2048
#define DM  768
#define NH  12
#define HD  64
#define MT  (Bsz * NT)   // 4096 tokens total
#define NCAT (3 * DM)    // 2304 concatenated Q,K,V output cols

typedef float    f32x4  __attribute__((ext_vector_type(4)));
typedef float    f32x16 __attribute__((ext_vector_type(16)));
typedef short    s16x8  __attribute__((ext_vector_type(8)));
typedef _Float16 f16x8  __attribute__((ext_vector_type(8)));
typedef int      v2i    __attribute__((ext_vector_type(2)));

#define GLOBAL_AS __attribute__((address_space(1)))
#define SHARED_AS __attribute__((address_space(3)))
#define LOG2E 1.44269504088896f

__device__ inline unsigned short f2h(float f) {
    union { _Float16 h; unsigned short u; } c; c.h = (_Float16)f; return c.u;
}
__device__ inline f16x8 ldh(const short* p) {
    return __builtin_bit_cast(f16x8, *(const s16x8*)p);
}
__device__ inline float exp2i(float x) {   // raw v_exp_f32: 2^x, 1 instruction
    float r;
    asm("v_exp_f32 %0, %1" : "=v"(r) : "v"(x));
    return r;
}
__device__ inline int cvtpkh(float lo, float hi_) {   // packs (lo,hi) -> 2xf16 dword
    int r;
    asm("v_cvt_pkrtz_f16_f32 %0, %1, %2" : "=v"(r) : "v"(lo), "v"(hi_));
    return r;
}
__device__ inline void plswap(int& a, int& b) {
    v2i r = __builtin_amdgcn_permlane32_swap(a, b, false, false);
    a = r[0]; b = r[1];
}
__device__ inline f16x8 mk8(int a, int b, int c, int d) {
    union { int i[4]; f16x8 v; } u;
    u.i[0] = a; u.i[1] = b; u.i[2] = c; u.i[3] = d;
    return u.v;
}
#define mfma32 __builtin_amdgcn_mfma_f32_32x32x16_f16
#define mfma16 __builtin_amdgcn_mfma_f32_16x16x32_f16

// ---------------- conversion kernels (f32 -> f16) ----------------

__global__ __launch_bounds__(256) void cvt_x_kernel(const float* __restrict__ x,
                                                    short* __restrict__ xf, int n8) {
    int i = blockIdx.x * blockDim.x + threadIdx.x;
    if (i >= n8) return;
    const float4* p = (const float4*)x + (size_t)i * 2;
    float4 a = p[0], b = p[1];
    float v[8] = {a.x, a.y, a.z, a.w, b.x, b.y, b.z, b.w};
    union { unsigned short s[8]; uint4 q; } H;
#pragma unroll
    for (int j = 0; j < 8; ++j) H.s[j] = f2h(v[j]);
    ((uint4*)xf)[i] = H.q;
}

__global__ __launch_bounds__(256) void cvt_w_kernel(const float* __restrict__ Wq,
                                                    const float* __restrict__ Wk,
                                                    const float* __restrict__ Wv,
                                                    short* __restrict__ Wf, int per8) {
    int i = blockIdx.x * blockDim.x + threadIdx.x;
    if (i >= 3 * per8) return;
    const float* src; int j;
    if (i < per8)          { src = Wq; j = i; }
    else if (i < 2 * per8) { src = Wk; j = i - per8; }
    else                   { src = Wv; j = i - 2 * per8; }
    const float4* p = (const float4*)src + (size_t)j * 2;
    float4 a = p[0], b = p[1];
    float v[8] = {a.x, a.y, a.z, a.w, b.x, b.y, b.z, b.w};
    union { unsigned short s[8]; uint4 q; } H;
#pragma unroll
    for (int t = 0; t < 8; ++t) H.s[t] = f2h(v[t]);
    ((uint4*)Wf)[i] = H.q;
}

// ---------------- QKV projection: y = x @ Wcat^T, all f16 (unchanged) ----------------

#define BM 128
#define BK 32
#define KSTEPS (DM / BK)   // 24

__global__ __launch_bounds__(256, 2) void qkv_proj_kernel(
        const short* __restrict__ xf, const short* __restrict__ Wf,
        short* __restrict__ Qf, short* __restrict__ Kf, short* __restrict__ Vf) {
    __shared__ short lds[2][2][BM * BK];   // [dbuf][A,B][row*32+k]

    const int tid = threadIdx.x;
    const int w = tid >> 6, lane = tid & 63;
    const int l15 = lane & 15, lg = lane >> 4;
    const int wr = w >> 1, wc = w & 1;

    const int tile_m = blockIdx.x * BM;
    const int tile_n = blockIdx.y * BM;    // concatenated col base

    const int arr = w >> 1, hlf = w & 1;
    const int srow = lane >> 2;            // 0..15
    const int scol = (lane & 3) * 8;       // element offset in row
    const short* gsrc = (arr == 0) ? xf + (size_t)tile_m * DM
                                   : Wf + (size_t)tile_n * DM;
    const short* gsrc_lane = gsrc + (size_t)(hlf * 64 + srow) * DM + scol;

    f32x4 zero4 = {0.f, 0.f, 0.f, 0.f};
    f32x4 acc[4][4];
#pragma unroll
    for (int i = 0; i < 4; ++i)
#pragma unroll
        for (int j = 0; j < 4; ++j) acc[i][j] = zero4;

    auto stage = [&](int buf, int kt) {
        const short* g = gsrc_lane + kt * BK;
#pragma unroll
        for (int j = 0; j < 4; ++j) {
            __builtin_amdgcn_global_load_lds(
                (const GLOBAL_AS void*)(g + (size_t)j * 16 * DM),
                (SHARED_AS void*)(&lds[buf][arr][(hlf * 64 + j * 16) * BK]),
                16, 0, 0);
        }
    };

    stage(0, 0);
    int cur = 0;
    for (int kt = 0; kt < KSTEPS; ++kt) {
        __syncthreads();                       // buf[cur] staged; prior reads drained
        if (kt + 1 < KSTEPS) stage(cur ^ 1, kt + 1);   // flies under the MFMAs

        f16x8 a[4], b[4];
#pragma unroll
        for (int f = 0; f < 4; ++f) {
            a[f] = ldh(&lds[cur][0][(wr * 64 + f * 16 + l15) * BK + lg * 8]);
            b[f] = ldh(&lds[cur][1][(wc * 64 + f * 16 + l15) * BK + lg * 8]);
        }
#pragma unroll
        for (int mf = 0; mf < 4; ++mf)
#pragma unroll
            for (int nf = 0; nf < 4; ++nf)
                acc[mf][nf] = mfma16(a[mf], b[nf], acc[mf][nf], 0, 0, 0);
        cur ^= 1;
    }

    // ---- epilogue ----
    const int zq = tile_n / DM;            // 0=Q 1=K 2=V (tiles never straddle)
    const int ncol0 = tile_n % DM;
#pragma unroll
    for (int mf = 0; mf < 4; ++mf) {
#pragma unroll
        for (int nf = 0; nf < 4; ++nf) {
            int col = ncol0 + wc * 64 + nf * 16 + l15;
            int h = col >> 6, dh = col & 63;
            int m0 = tile_m + wr * 64 + mf * 16 + lg * 4;
            int b2 = m0 >> 11, nt0 = m0 & (NT - 1);
            int bh_ = b2 * NH + h;
            if (zq == 2) {
                union { short s[4]; short4 v; } pk;
#pragma unroll
                for (int r = 0; r < 4; ++r) pk.s[r] = (short)f2h(acc[mf][nf][r]);
                *(short4*)&Vf[((size_t)bh_ * HD + dh) * NT + nt0] = pk.v;  // V transposed
            } else {
                short* Hp = (zq == 0) ? Qf : Kf;
                float scl = (zq == 0) ? LOG2E : 1.0f;   // Q in log2-domain
#pragma unroll
                for (int r = 0; r < 4; ++r) {
                    size_t oidx = ((size_t)bh_ * NT + nt0 + r) * HD + dh;
                    Hp[oidx] = (short)f2h(acc[mf][nf][r] * scl);
                }
            }
        }
    }
}

// ---------------- attention partials: split-KV flash, f16, log2-domain ----------
// grid (40, B*H): round-7 slot map, SEGT=8 (2-8 tiles/slot, 960 blocks).
// Per 64-row KV tile: TWO interleaved S-MFMA chains (Sa,Sb) then ONE combined
// online-softmax update (1 max-shfl, 1 defer-check/rescale, 1 sum-shfl) —
// halves the serial softmax-state chain vs per-32-col updates.
// o0[r] holds O[q-row kr][d-col l31]; per-row scalars go through ds_bpermute(kr).

#define QB  128
#define KVB 64
#define NQB (NT / QB)     // 16
#define SEGT 8            // KV tiles per segment
#define SLOTS 40          // per bh
#define OPA 600           // Op slots aliased into the dead xf/Wf region (exact fit)

__global__ __launch_bounds__(256) void attn_part_kernel(const short* __restrict__ Qf,
                                                        const short* __restrict__ Kf,
                                                        const short* __restrict__ Vf,
                                                        short* __restrict__ OpA_,
                                                        short* __restrict__ OpB_,
                                                        float2* __restrict__ ml) {
    const int s = blockIdx.x;
    int qb, seg;
    if (s < 4)       { qb = s;                  seg = 0; }
    else if (s < 12) { qb = 4 + ((s - 4) >> 1);   seg = (s - 4) & 1; }
    else if (s < 24) { qb = 8 + (s - 12) / 3;     seg = (s - 12) % 3; }
    else             { qb = 12 + ((s - 24) >> 2); seg = (s - 24) & 3; }
    const int bh = blockIdx.y;
    const int g = bh * SLOTS + s;
    const int tid = threadIdx.x;
    const int w = tid >> 6, lane = tid & 63;
    const int l31 = lane & 31, hi = lane >> 5;

    __shared__ __align__(16) short lds[2][2 * 4096];   // [dbuf][K|V^T][64*64]

    const size_t kvoff = (size_t)bh * NT * HD;
    const short* Kfb = Kf + kvoff;
    const short* Vb  = Vf + (size_t)bh * HD * NT;

    // per-thread staging descriptors: 4 x 16B chunks per tile
    const short* sbase[4]; int sstr[4]; int sdof[4];
#pragma unroll
    for (int k = 0; k < 4; ++k) {
        int c = tid + 256 * k;
        int arr = c >> 9, idx = c & 511;
        int row = idx >> 3, ch = idx & 7;
        if (arr == 0) { sbase[k] = Kfb + (size_t)row * HD + ch * 8; sstr[k] = KVB * HD; }
        else          { sbase[k] = Vb + (size_t)row * NT + ch * 8;  sstr[k] = KVB; }
        sdof[k] = arr * 4096 + row * 64 + ((ch ^ (row & 7)) << 3);
    }

    const int q0w   = qb * QB + w * 32;
    const int qg    = q0w + l31;       // this lane's q-row
    const int qmaxw = q0w + 31;

    // Q fragments (B-operand layout: lane = q-row l31, k = c*16+hi*8); log2-scaled
    f16x8 qf[4];
    const size_t qrow = kvoff + (size_t)qg * HD;
#pragma unroll
    for (int c = 0; c < 4; ++c) qf[c] = ldh(Qf + qrow + c * 16 + hi * 8);

    f32x16 o0{}, o1{};
    float m_run = -1e30f, l_run = 0.f;

    const int t0   = seg * SEGT;
    const int tend = min(t0 + SEGT, 2 * qb + 2);

    {   // prologue: stage tile t0 into buf 0
        uint4 ld0[4];
#pragma unroll
        for (int k = 0; k < 4; ++k) ld0[k] = *(const uint4*)(sbase[k] + (size_t)t0 * sstr[k]);
#pragma unroll
        for (int k = 0; k < 4; ++k) *(uint4*)(&lds[0][sdof[k]]) = ld0[k];
    }

    for (int t = t0; t < tend; ++t) {
        __syncthreads();                      // current buf staged for all waves
        const int cur = (t - t0) & 1;
        const int kv0 = t * KVB;
        const bool haveNext = (t + 1 < tend);
        uint4 ldn[4];
        if (haveNext) {                       // issue early; lands under compute
#pragma unroll
            for (int k = 0; k < 4; ++k)
                ldn[k] = *(const uint4*)(sbase[k] + (size_t)(t + 1) * sstr[k]);
        }

        if (kv0 <= qmaxw) {                   // wave-uniform causal tile skip
            const short* Ks = &lds[cur][0];
            const short* Vs = &lds[cur][4096];
            // ---- S for BOTH 32-row halves: two interleaved MFMA chains ----
            f32x16 Sa{}, Sb{};
            const int swbA = l31 * 64;
            const int swbB = (32 + l31) * 64;
            const int sw7  = l31 & 7;          // (32+l31)&7 == l31&7
#pragma unroll
            for (int c = 0; c < 4; ++c) {
                int sh = (((c << 1) + hi) ^ sw7) << 3;
                Sa = mfma32(ldh(&Ks[swbA + sh]), qf[c], Sa, 0, 0, 0);
                Sb = mfma32(ldh(&Ks[swbB + sh]), qf[c], Sb, 0, 0, 0);
            }
            const bool haveB = (kv0 + 32 <= qmaxw);
            // ---- mask (diagonal only) + combined lane-local max ----
            float pmax = -3e38f;
            if (kv0 + 31 > q0w) {
#pragma unroll
                for (int r = 0; r < 16; ++r) {
                    int kvg = kv0 + (r & 3) + 8 * (r >> 2) + 4 * hi;
                    Sa[r] = (kvg > qg) ? -3e38f : Sa[r];
                    pmax = fmaxf(pmax, Sa[r]);
                }
            } else {
#pragma unroll
                for (int r = 0; r < 16; ++r) pmax = fmaxf(pmax, Sa[r]);
            }
            if (haveB) {
                if (kv0 + 63 > q0w) {
#pragma unroll
                    for (int r = 0; r < 16; ++r) {
                        int kvg = kv0 + 32 + (r & 3) + 8 * (r >> 2) + 4 * hi;
                        Sb[r] = (kvg > qg) ? -3e38f : Sb[r];
                        pmax = fmaxf(pmax, Sb[r]);
                    }
                } else {
#pragma unroll
                    for (int r = 0; r < 16; ++r) pmax = fmaxf(pmax, Sb[r]);
                }
            }
            pmax = fmaxf(pmax, __shfl_xor(pmax, 32));
            // ---- ONE defer-max online-softmax update per 64-row tile ----
            if (!__all(pmax - m_run <= 11.5416f)) {
                float mn = fmaxf(m_run, pmax);
                float al = exp2i(m_run - mn);
                m_run = mn; l_run *= al;
                int ai = __builtin_bit_cast(int, al);
#pragma unroll
                for (int r = 0; r < 16; ++r) {
                    int kr = (r & 3) + 8 * (r >> 2) + 4 * hi;
                    float av = __builtin_bit_cast(float,
                                  __builtin_amdgcn_ds_bpermute(kr << 2, ai));
                    o0[r] *= av; o1[r] *= av;
                }
            }
            float rs = 0.f;
#pragma unroll
            for (int r = 0; r < 16; ++r) { Sa[r] = exp2i(Sa[r] - m_run); rs += Sa[r]; }
            if (haveB) {
#pragma unroll
                for (int r = 0; r < 16; ++r) { Sb[r] = exp2i(Sb[r] - m_run); rs += Sb[r]; }
            }
            rs += __shfl_xor(rs, 32);
            l_run += rs;
            // ---- pack + PV, half A (chunks 0..3) ----
            {
                int cpk[8];
#pragma unroll
                for (int i = 0; i < 8; ++i) cpk[i] = cvtpkh(Sa[2 * i], Sa[2 * i + 1]);
                int a0 = cpk[0], b0 = cpk[2]; plswap(a0, b0);
                int a1 = cpk[1], b1 = cpk[3]; plswap(a1, b1);
                int a2 = cpk[4], b2 = cpk[6]; plswap(a2, b2);
                int a3 = cpk[5], b3 = cpk[7]; plswap(a3, b3);
                f16x8 pf[2] = { mk8(a0, a1, b0, b1), mk8(a2, a3, b2, b3) };
#pragma unroll
                for (int kc = 0; kc < 2; ++kc) {
                    int chunk = kc * 2 + hi;
                    int sh = (chunk ^ (l31 & 7)) << 3;
                    o0 = mfma32(pf[kc], ldh(&Vs[l31 * 64 + sh]), o0, 0, 0, 0);
                    o1 = mfma32(pf[kc], ldh(&Vs[(32 + l31) * 64 + sh]), o1, 0, 0, 0);
                }
            }
            // ---- pack + PV, half B (chunks 4..7) ----
            if (haveB) {
                int cpk[8];
#pragma unroll
                for (int i = 0; i < 8; ++i) cpk[i] = cvtpkh(Sb[2 * i], Sb[2 * i + 1]);
                int a0 = cpk[0], b0 = cpk[2]; plswap(a0, b0);
                int a1 = cpk[1], b1 = cpk[3]; plswap(a1, b1);
                int a2 = cpk[4], b2 = cpk[6]; plswap(a2, b2);
                int a3 = cpk[5], b3 = cpk[7]; plswap(a3, b3);
                f16x8 pf[2] = { mk8(a0, a1, b0, b1), mk8(a2, a3, b2, b3) };
#pragma unroll
                for (int kc = 0; kc < 2; ++kc) {
                    int chunk = 4 + kc * 2 + hi;
                    int sh = (chunk ^ (l31 & 7)) << 3;
                    o0 = mfma32(pf[kc], ldh(&Vs[l31 * 64 + sh]), o0, 0, 0, 0);
                    o1 = mfma32(pf[kc], ldh(&Vs[(32 + l31) * 64 + sh]), o1, 0, 0, 0);
                }
            }
        }

        if (haveNext) {                       // write next tile into other buffer
#pragma unroll
            for (int k = 0; k < 4; ++k) *(uint4*)(&lds[cur ^ 1][sdof[k]]) = ldn[k];
        }
    }

    // ---- epilogue: normalized partial O (f16) + (m,l) per row ----
    float inv = 1.0f / l_run;
    int ii = __builtin_bit_cast(int, inv);
    short* op = (g < OPA) ? OpA_ + (size_t)g * (QB * HD)
                          : OpB_ + (size_t)(g - OPA) * (QB * HD);
#pragma unroll
    for (int r = 0; r < 16; ++r) {
        int kr = (r & 3) + 8 * (r >> 2) + 4 * hi;
        float iv = __builtin_bit_cast(float, __builtin_amdgcn_ds_bpermute(kr << 2, ii));
        short* orow = op + (w * 32 + kr) * HD;
        orow[l31]      = (short)f2h(o0[r] * iv);
        orow[32 + l31] = (short)f2h(o1[r] * iv);
    }
    if (hi == 0) {
        float2 v; v.x = m_run; v.y = l_run;   // m in log2-domain
        ml[(size_t)g * QB + w * 32 + l31] = v;
    }
}

// ---------------- combine: merge split-KV partials (base-2 weights) ----------------

__global__ __launch_bounds__(256) void combine_kernel(const short* __restrict__ OpA_,
                                                      const short* __restrict__ OpB_,
                                                      const float2* __restrict__ ml,
                                                      float* __restrict__ out) {
    const int qb = blockIdx.x, bh = blockIdx.y;
    const int b = bh / NH, h = bh % NH;
    const int nseg = (qb >> 2) + 1;
    const int baseg[4] = {0, 4, 12, 24};
    const int sbase = baseg[qb >> 2] + (qb & 3) * nseg;
    const int row = threadIdx.x >> 1;
    const int c0 = (threadIdx.x & 1) * 32;

    float m[4], l[4];
    float M = -3e38f;
    for (int s2 = 0; s2 < nseg; ++s2) {
        float2 t = ml[((size_t)(bh * SLOTS + sbase + s2)) * QB + row];
        m[s2] = t.x; l[s2] = t.y;
        M = fmaxf(M, t.x);
    }
    float wgt[4], L = 0.f;
    for (int s2 = 0; s2 < nseg; ++s2) {
        float e;
        asm("v_exp_f32 %0, %1" : "=v"(e) : "v"(m[s2] - M));   // 2^(m-M), log2-domain
        wgt[s2] = l[s2] * e; L += wgt[s2];
    }
    float invL = 1.0f / L;

    float acc[32];
#pragma unroll
    for (int j = 0; j < 32; ++j) acc[j] = 0.f;
    for (int s2 = 0; s2 < nseg; ++s2) {
        int g = bh * SLOTS + sbase + s2;
        const short* opg = (g < OPA) ? OpA_ + (size_t)g * (QB * HD)
                                     : OpB_ + (size_t)(g - OPA) * (QB * HD);
        const short* oprow = opg + (size_t)row * HD + c0;
        float wg = wgt[s2] * invL;
#pragma unroll
        for (int v = 0; v < 4; ++v) {
            f16x8 d = ldh(oprow + v * 8);
#pragma unroll
            for (int j = 0; j < 8; ++j)
                acc[v * 8 + j] += wg * (float)d[j];
        }
    }
    float* orow = out + ((size_t)(b * NT + qb * QB + row)) * DM + h * HD + c0;
#pragma unroll
    for (int j = 0; j < 32; ++j) orow[j] = acc[j];
}

// ---------------- launch ----------------

extern "C" void kernel_launch(void* const* d_in, const int* in_sizes, int n_in,
                              void* d_out, int out_size, void* d_ws, size_t ws_size,
                              hipStream_t stream) {
    const float* x  = (const float*)d_in[0];
    const float* Wq = (const float*)d_in[1];
    const float* Wk = (const float*)d_in[2];
    const float* Wv = (const float*)d_in[3];
    float* outp = (float*)d_out;

    const size_t MD = (size_t)MT * DM;   // 3,145,728
    const size_t DD = (size_t)DM * DM;   //   589,824

    short* wsp = (short*)d_ws;
    short* xf = wsp;            // MD
    short* Wf = xf + MD;        // 3*DD   (xf+Wf = 4,915,200 shorts = 600 Op slots exactly)
    short* Qf = Wf + 3 * DD;    // MD
    short* Kf = Qf + MD;        // MD
    short* Vf = Kf + MD;        // MD (transposed: [bh][hd][n])
    // Op partials: region A aliases dead xf/Wf (600 slots), region B after Vf.
    short* OpA_ = wsp;
    short* OpB_ = Vf + MD;      // (40*24-600) = 360 slots x 8192 shorts
    float2* mlp = (float2*)(OpB_ + (size_t)360 * QB * HD);   // 960*128 float2

    int n8x = (int)(MD / 8);
    cvt_x_kernel<<<dim3((n8x + 255) / 256), 256, 0, stream>>>(x, xf, n8x);
    int per8 = (int)(DD / 8);
    cvt_w_kernel<<<dim3((3 * per8 + 255) / 256), 256, 0, stream>>>(Wq, Wk, Wv, Wf, per8);
    qkv_proj_kernel<<<dim3(MT / BM, NCAT / BM), 256, 0, stream>>>(xf, Wf, Qf, Kf, Vf);
    attn_part_kernel<<<dim3(SLOTS, Bsz * NH), 256, 0, stream>>>(Qf, Kf, Vf, OpA_, OpB_, mlp);
    combine_kernel<<<dim3(NQB, Bsz * NH), 256, 0, stream>>>(OpA_, OpB_, mlp, outp);
}